// Round 5
// baseline (489.143 us; speedup 1.0000x reference)
//
#include <hip/hip_runtime.h>

#define N_SEQ 16384
#define LSEQ  512
#define VOCAB 32000
#define ES    32
#define HS    64
#define LDH   72    // padded f16 stride per m-row in LDS
#define TS    18    // tok stride in u16 (transposed [t][s], odd dword stride)
#define RT    1024  // tok data rows per group (chain <= 1024 always; +2 pad rows)
#define NBLK  256   // 256 blocks x 2 chain-groups = 512 groups = 8192 chains

#define SC_RZ (-1.4426950408889634f)   // -log2(e): folded into r,z weights
#define SC_N  (-2.8853900817779268f)   // -2*log2(e): folded into n weights

typedef _Float16 v8h __attribute__((ext_vector_type(8)));
typedef float    v4f __attribute__((ext_vector_type(4)));

// ---------------- K_len: wave-per-row nonzero count (coalesced int4) --------
__global__ __launch_bounds__(256) void k_len(const int* __restrict__ x,
                                             int* __restrict__ len,
                                             int* __restrict__ hist){
  int row  = blockIdx.x * 4 + (threadIdx.x >> 6);
  int lane = threadIdx.x & 63;
  const int4* xr = (const int4*)(x + (size_t)row * LSEQ);
  int cnt = 0;
  #pragma unroll
  for (int i = 0; i < 2; ++i){
    int4 v = xr[lane + i*64];
    cnt += (v.x != 0) + (v.y != 0) + (v.z != 0) + (v.w != 0);
  }
  #pragma unroll
  for (int d = 1; d < 64; d <<= 1) cnt += __shfl_xor(cnt, d, 64);
  if (lane == 0){ len[row] = cnt; atomicAdd(&hist[cnt], 1); }
}

// ---------------- K_mid: scatter | emb->f16 (vectorized) | weight packs -----
#define SCB   16
#define EMBV  125
__global__ __launch_bounds__(1024) void k_mid(const int* __restrict__ hist,
                                              const int* __restrict__ len,
                                              int* __restrict__ gcnt,
                                              int* __restrict__ perm,
                                              const float* __restrict__ emb,
                                              const float* __restrict__ whh,
                                              const float* __restrict__ wih,
                                              _Float16* __restrict__ ef,
                                              _Float16* __restrict__ wpk,
                                              _Float16* __restrict__ wpe){
  int b = blockIdx.x;
  if (b < SCB){                               // ---- scan + scatter
    __shared__ int buf[1024];
    __shared__ int offs[513];
    int i = threadIdx.x;
    buf[i] = (i < 513) ? hist[i] : 0;
    __syncthreads();
    for (int d = 1; d < 1024; d <<= 1){
      int v = (i >= d) ? buf[i - d] : 0;
      __syncthreads();
      buf[i] += v;
      __syncthreads();
    }
    if (i < 513) offs[i] = (i == 0) ? 0 : buf[i - 1];
    __syncthreads();
    int s = b * 1024 + i;
    int l = len[s];
    int pos = offs[l] + atomicAdd(&gcnt[l], 1);
    perm[pos] = s;                            // perm ascending by length
  } else if (b < SCB + EMBV){                 // ---- emb f32 -> f16, 8/thread
    int i = ((b - SCB) * 1024 + threadIdx.x) * 8;
    float4 f0 = *(const float4*)(emb + i);
    float4 f1 = *(const float4*)(emb + i + 4);
    v8h o;
    o[0] = (_Float16)f0.x; o[1] = (_Float16)f0.y;
    o[2] = (_Float16)f0.z; o[3] = (_Float16)f0.w;
    o[4] = (_Float16)f1.x; o[5] = (_Float16)f1.y;
    o[6] = (_Float16)f1.z; o[7] = (_Float16)f1.w;
    *(v8h*)(ef + i) = o;
  } else {                                    // ---- weight packs (3 blocks)
    int tid = (b - SCB - EMBV) * 1024 + threadIdx.x;
    if (tid < 1536){                          // w_hh: 24 frags
      int f = tid >> 6, l = tid & 63;
      int jt = f >> 1, kf = f & 1;
      float sc = (jt < 8) ? SC_RZ : SC_N;
      #pragma unroll
      for (int i = 0; i < 8; ++i){
        int row = jt * 16 + (l & 15);
        int col = kf * 32 + (l >> 4) * 8 + i;
        wpk[(size_t)tid * 8 + i] = (_Float16)(sc * whh[row * HS + col]);
      }
    } else if (tid < 1536 + 768){             // w_ih: 12 frags
      int t2 = tid - 1536;
      int tile = t2 >> 6, l = t2 & 63;
      float sc = ((tile >> 2) < 2) ? SC_RZ : SC_N;
      #pragma unroll
      for (int i = 0; i < 8; ++i){
        int row = tile * 16 + (l & 15);
        int col = (l >> 4) * 8 + i;
        wpe[(size_t)t2 * 8 + i] = (_Float16)(sc * wih[row * ES + col]);
      }
    }
  }
}

// ---------------- K3: recurrence (2 chain-groups / block, 1 bar / 2 steps) --
// R4 measured: balanced 2-waves/SIMD -> step latency L=1410cyc is the wall
// (wall = 514*L; SIMD issues only 828 of it -> VALUBusy 58.6%). This round:
// each 256-thr block fuses TWO chain-groups A,B; per round [A-step][B-step]
// then ONE lgkmcnt+barrier. A's LDS write->read turnaround spans B's whole
// phase + barrier (drain hidden); the compiler interleaves the independent
// A/B chains inside the wave; 256 blocks = 1 block/CU -> the 4-wave barrier
// has no foreign-wave jitter and barrier count is halved.
__global__ __launch_bounds__(256, 1) void k_gru(
    const int* __restrict__ x, const _Float16* __restrict__ ef,
    const _Float16* __restrict__ wpk, const _Float16* __restrict__ wpe,
    const float* __restrict__ bih, const float* __restrict__ bhh,
    const int* __restrict__ perm, const int* __restrict__ len,
    float* __restrict__ out)
{
  __shared__ __align__(16) _Float16 hbA[2][16 * LDH];
  __shared__ __align__(16) _Float16 hbB[2][16 * LDH];
  __shared__ unsigned short tokA[(RT + 2) * TS];
  __shared__ unsigned short tokB[(RT + 2) * TS];
  __shared__ int sP[32], sQ[32], sL1[32], sL2[32];
  int qt   = threadIdx.x >> 6;
  int lane = threadIdx.x & 63;
  int q = lane >> 4, c = lane & 15;
  int uu = qt*16 + c;

  v8h bfh[3][2], bfe[3];
  #pragma unroll
  for (int g = 0; g < 3; ++g){
    int tile = g*4 + qt;
    #pragma unroll
    for (int kf = 0; kf < 2; ++kf)
      bfh[g][kf] = *(const v8h*)(wpk + ((size_t)(tile*2 + kf)*64 + lane)*8);
    bfe[g] = *(const v8h*)(wpe + ((size_t)tile*64 + lane)*8);
  }

  if (threadIdx.x < 32){                      // chain metadata -> LDS
    int ch = blockIdx.x*32 + threadIdx.x;
    int p  = perm[(N_SEQ - 1) - ch];          // long seq
    int q2 = perm[ch];                        // short seq
    sP[threadIdx.x] = p;       sQ[threadIdx.x] = q2;
    sL1[threadIdx.x] = len[p]; sL2[threadIdx.x] = len[q2];
  }
  for (int i = threadIdx.x; i < 16*LDH; i += 256){
    hbA[0][i] = (_Float16)0.f;
    hbB[0][i] = (_Float16)0.f;
  }
  __syncthreads();

  int psA[4], qsA[4], lnPA[4], lnTA[4];
  int psB[4], qsB[4], lnPB[4], lnTB[4];
  #pragma unroll
  for (int r = 0; r < 4; ++r){
    int j = q*4 + r;
    psA[r] = sP[j];      qsA[r] = sQ[j];
    lnPA[r] = sL1[j];    lnTA[r] = sL1[j] + sL2[j];
    psB[r] = sP[j+16];   qsB[r] = sQ[j+16];
    lnPB[r] = sL1[j+16]; lnTB[r] = sL1[j+16] + sL2[j+16];
  }

  float br  = SC_RZ * (bih[uu]      + bhh[uu]);
  float bz  = SC_RZ * (bih[HS + uu] + bhh[HS + uu]);
  float ben = SC_N  *  bih[2*HS + uu];
  float bhn = SC_N  *  bhh[2*HS + uu];
  v4f brq  = {br, br, br, br};
  v4f bzq  = {bz, bz, bz, bz};
  v4f benq = {ben, ben, ben, ben};
  v4f bhnq = {bhn, bhn, bhn, bhn};

  float hA[4], hB[4];
  #pragma unroll
  for (int r = 0; r < 4; ++r){ hA[r] = 0.f; hB[r] = 0.f; }

  // stage both groups' chain token streams
  for (int i = threadIdx.x; i < 32*RT; i += 256){
    int ch = i >> 10, tt = i & (RT-1);
    int l1 = sL1[ch];
    int isA = tt < l1;
    int tb = tt - l1; tb = tb < 511 ? tb : 511;
    int seq = isA ? sP[ch] : sQ[ch];
    int tc  = isA ? tt : tb;
    unsigned short v = (unsigned short)x[(size_t)seq * LSEQ + tc];
    if (ch < 16) tokA[tt*TS + ch] = v; else tokB[tt*TS + (ch-16)] = v;
  }
  if (threadIdx.x < 64){                      // zero pad rows RT, RT+1
    int g = threadIdx.x >> 5, rr = (threadIdx.x >> 4) & 1, s = threadIdx.x & 15;
    (g ? tokB : tokA)[(RT + rr)*TS + s] = 0;
  }
  __syncthreads();

  int tmax = 0, tmin = RT;
  #pragma unroll
  for (int r = 0; r < 4; ++r){
    tmax = max(tmax, max(lnTA[r], lnTB[r]));
    tmin = min(tmin, min(lnTA[r], lnTB[r]));
  }
  tmax = max(tmax, __shfl_xor(tmax, 16, 64));
  tmax = max(tmax, __shfl_xor(tmax, 32, 64));
  tmin = min(tmin, __shfl_xor(tmin, 16, 64));
  tmin = min(tmin, __shfl_xor(tmin, 32, 64));

  v8h aecA, aenA, aecB, aenB;
  v4f praA, prbA, pzaA, pzbA, deaA, debA;
  v4f praB, prbB, pzaB, pzbB, deaB, debB;
  {
    int tk0 = tokA[0*TS + c];
    aecA = *(const v8h*)(ef + (size_t)tk0 * ES + q*8);
    praA = __builtin_amdgcn_mfma_f32_16x16x32_f16(aecA, bfe[0], brq,  0,0,0);
    pzaA = __builtin_amdgcn_mfma_f32_16x16x32_f16(aecA, bfe[1], bzq,  0,0,0);
    deaA = __builtin_amdgcn_mfma_f32_16x16x32_f16(aecA, bfe[2], benq, 0,0,0);
    int tk1 = tokA[1*TS + c];
    aenA = *(const v8h*)(ef + (size_t)tk1 * ES + q*8);
    int tk0b = tokB[0*TS + c];
    aecB = *(const v8h*)(ef + (size_t)tk0b * ES + q*8);
    praB = __builtin_amdgcn_mfma_f32_16x16x32_f16(aecB, bfe[0], brq,  0,0,0);
    pzaB = __builtin_amdgcn_mfma_f32_16x16x32_f16(aecB, bfe[1], bzq,  0,0,0);
    deaB = __builtin_amdgcn_mfma_f32_16x16x32_f16(aecB, bfe[2], benq, 0,0,0);
    int tk1b = tokB[1*TS + c];
    aenB = *(const v8h*)(ef + (size_t)tk1b * ES + q*8);
  }

  #define GRU_PHASE(TOK, HB, H, LNP, LNT, SEQP, PRR, PRZ, DEN, PRRn, PRZn, DENn, ACONS, ALOAD, FREEZE, RB, WB) \
  {                                                                            \
    int tkn = TOK[(t + 2)*TS + c];                                             \
    v8h a0 = *(const v8h*)(&HB[RB][c*LDH + q*8]);                              \
    v8h a1 = *(const v8h*)(&HB[RB][c*LDH + 32 + q*8]);                         \
    v4f zr  = __builtin_amdgcn_mfma_f32_16x16x32_f16(a1, bfh[0][1], PRR, 0,0,0);\
    v4f Dr  = __builtin_amdgcn_mfma_f32_16x16x32_f16(a0, bfh[0][0], zr,  0,0,0);\
    v4f zz  = __builtin_amdgcn_mfma_f32_16x16x32_f16(a1, bfh[1][1], PRZ, 0,0,0);\
    v4f Dz  = __builtin_amdgcn_mfma_f32_16x16x32_f16(a0, bfh[1][0], zz,  0,0,0);\
    v4f zh  = __builtin_amdgcn_mfma_f32_16x16x32_f16(a1, bfh[2][1], bhnq,0,0,0);\
    v4f Dhn = __builtin_amdgcn_mfma_f32_16x16x32_f16(a0, bfh[2][0], zh,  0,0,0);\
    _Pragma("unroll")                                                          \
    for (int r = 0; r < 4; ++r){                                               \
      float rg   = __builtin_amdgcn_rcpf(1.f + __builtin_amdgcn_exp2f(Dr[r])); \
      float zg   = __builtin_amdgcn_rcpf(1.f + __builtin_amdgcn_exp2f(Dz[r])); \
      float te   = __builtin_amdgcn_exp2f(DEN[r] + rg * Dhn[r]);               \
      float ng   = fmaf(2.f, __builtin_amdgcn_rcpf(1.f + te), -1.f);           \
      float hnew = ng + zg * (H[r] - ng);                                      \
      H[r]       = (FREEZE && t >= LNT[r]) ? H[r] : hnew;                      \
    }                                                                          \
    {                                                                          \
      int f0 = (t + 1 == LNP[0]), f1 = (t + 1 == LNP[1]);                      \
      int f2 = (t + 1 == LNP[2]), f3 = (t + 1 == LNP[3]);                      \
      if (f0 | f1 | f2 | f3){                                                  \
        if (f0){ out[(size_t)SEQP[0]*HS + uu] = H[0]; H[0] = 0.f; }            \
        if (f1){ out[(size_t)SEQP[1]*HS + uu] = H[1]; H[1] = 0.f; }            \
        if (f2){ out[(size_t)SEQP[2]*HS + uu] = H[2]; H[2] = 0.f; }            \
        if (f3){ out[(size_t)SEQP[3]*HS + uu] = H[3]; H[3] = 0.f; }            \
      }                                                                        \
    }                                                                          \
    PRRn = __builtin_amdgcn_mfma_f32_16x16x32_f16(ACONS, bfe[0], brq,  0,0,0); \
    PRZn = __builtin_amdgcn_mfma_f32_16x16x32_f16(ACONS, bfe[1], bzq,  0,0,0); \
    DENn = __builtin_amdgcn_mfma_f32_16x16x32_f16(ACONS, bfe[2], benq, 0,0,0); \
    ALOAD = *(const v8h*)(ef + (size_t)tkn * ES + q*8);  /* emb t+2 */         \
    _Pragma("unroll")                                                          \
    for (int r = 0; r < 4; ++r)                                                \
      HB[WB][(q*4 + r)*LDH + uu] = (_Float16)H[r];                             \
  }

  #define ROUND_EVEN(FREEZE)                                                   \
    GRU_PHASE(tokA, hbA, hA, lnPA, lnTA, psA, praA,pzaA,deaA, prbA,pzbA,debA, aenA, aecA, FREEZE, 0, 1); \
    GRU_PHASE(tokB, hbB, hB, lnPB, lnTB, psB, praB,pzaB,deaB, prbB,pzbB,debB, aenB, aecB, FREEZE, 0, 1); \
    asm volatile("s_waitcnt lgkmcnt(0)" ::: "memory");                         \
    __builtin_amdgcn_s_barrier();                                              \
    asm volatile("" ::: "memory");

  #define ROUND_ODD(FREEZE)                                                    \
    GRU_PHASE(tokA, hbA, hA, lnPA, lnTA, psA, prbA,pzbA,debA, praA,pzaA,deaA, aecA, aenA, FREEZE, 1, 0); \
    GRU_PHASE(tokB, hbB, hB, lnPB, lnTB, psB, prbB,pzbB,debB, praB,pzaB,deaB, aecB, aenB, FREEZE, 1, 0); \
    asm volatile("s_waitcnt lgkmcnt(0)" ::: "memory");                         \
    __builtin_amdgcn_s_barrier();                                              \
    asm volatile("" ::: "memory");

  int t = 0;
  for (; t + 1 < tmin; ){
    ROUND_EVEN(0); ++t;
    ROUND_ODD(0);  ++t;
  }
  for (; t + 1 < tmax; ){
    ROUND_EVEN(1); ++t;
    ROUND_ODD(1);  ++t;
  }
  if (t < tmax){
    ROUND_EVEN(1); ++t;
  }
  #undef ROUND_EVEN
  #undef ROUND_ODD
  #undef GRU_PHASE

  #pragma unroll
  for (int r = 0; r < 4; ++r){
    out[(size_t)qsA[r]*HS + uu] = hA[r];
    out[(size_t)qsB[r]*HS + uu] = hB[r];
    if (lnPA[r] == 0) out[(size_t)psA[r]*HS + uu] = 0.f;
    if (lnPB[r] == 0) out[(size_t)psB[r]*HS + uu] = 0.f;
  }
}

extern "C" void kernel_launch(void* const* d_in, const int* in_sizes, int n_in,
                              void* d_out, int out_size, void* d_ws, size_t ws_size,
                              hipStream_t stream){
  const int*   x   = (const int*)  d_in[0];
  const float* emb = (const float*)d_in[1];
  const float* wih = (const float*)d_in[2];
  const float* whh = (const float*)d_in[3];
  const float* bih = (const float*)d_in[4];
  const float* bhh = (const float*)d_in[5];
  float* out = (float*)d_out;

  char* ws = (char*)d_ws;
  size_t off = 0;
  _Float16* ef  = (_Float16*)(ws + off);  off += (size_t)VOCAB * ES * sizeof(_Float16);
  _Float16* wpk = (_Float16*)(ws + off);  off += (size_t)24 * 64 * 8 * sizeof(_Float16);
  _Float16* wpe = (_Float16*)(ws + off);  off += (size_t)12 * 64 * 8 * sizeof(_Float16);
  off = (off + 255) & ~(size_t)255;
  int* len  = (int*)(ws + off);           off += (size_t)N_SEQ * sizeof(int);
  int* perm = (int*)(ws + off);           off += (size_t)N_SEQ * sizeof(int);
  int* hist = (int*)(ws + off);           off += 513 * sizeof(int);
  int* gcnt = (int*)(ws + off);           off += 513 * sizeof(int);

  hipMemsetAsync(hist, 0, 2 * 513 * sizeof(int), stream);   // hist + gcnt
  k_len <<<N_SEQ / 4, 256, 0, stream>>>(x, len, hist);
  k_mid <<<SCB + EMBV + 3, 1024, 0, stream>>>(hist, len, gcnt, perm,
                                              emb, whh, wih, ef, wpk, wpe);
  k_gru <<<NBLK, 256, 0, stream>>>(x, ef, wpk, wpe, bih, bhh, perm, len, out);
}

// Round 6
// 322.457 us; speedup vs baseline: 1.5169x; 1.5169x over previous
//
#include <hip/hip_runtime.h>

#define N_SEQ 16384
#define LSEQ  512
#define VOCAB 32000
#define ES    32
#define HS    64
#define LDH   72    // padded f16 stride per m-row in LDS
#define TS    18    // tok stride in u16 (transposed [t][s], odd dword stride)

#define SC_RZ (-1.4426950408889634f)   // -log2(e): folded into r,z weights
#define SC_N  (-2.8853900817779268f)   // -2*log2(e): folded into n weights

typedef _Float16 v8h __attribute__((ext_vector_type(8)));
typedef float    v4f __attribute__((ext_vector_type(4)));

// ---------------- K1 (fused prep): lengths | emb->f16 | weight packs --------
#define NLB (N_SEQ / 4)            // 4096 blocks: wave-per-row length count
#define NEB (VOCAB * ES / 2048)    // 500 blocks: vectorized emb convert (8/thr)
__global__ __launch_bounds__(256) void k_prep(const int* __restrict__ x,
                                              const float* __restrict__ emb,
                                              const float* __restrict__ whh,
                                              const float* __restrict__ wih,
                                              int* __restrict__ len,
                                              int* __restrict__ hist,
                                              _Float16* __restrict__ ef,
                                              _Float16* __restrict__ wpk,
                                              _Float16* __restrict__ wpe){
  int b = blockIdx.x;
  if (b < NLB){                               // ---- lengths: coalesced count
    int row  = b * 4 + (threadIdx.x >> 6);
    int lane = threadIdx.x & 63;
    const int4* xr = (const int4*)(x + (size_t)row * LSEQ);
    int cnt = 0;
    #pragma unroll
    for (int i = 0; i < 2; ++i){
      int4 v = xr[lane + i*64];
      cnt += (v.x != 0) + (v.y != 0) + (v.z != 0) + (v.w != 0);
    }
    #pragma unroll
    for (int d = 1; d < 64; d <<= 1) cnt += __shfl_xor(cnt, d, 64);
    if (lane == 0){ len[row] = cnt; atomicAdd(&hist[cnt], 1); }
  } else if (b < NLB + NEB){                  // ---- emb f32 -> f16, 8/thread
    int i = ((b - NLB) * 256 + threadIdx.x) * 8;
    float4 f0 = *(const float4*)(emb + i);
    float4 f1 = *(const float4*)(emb + i + 4);
    v8h o;
    o[0] = (_Float16)f0.x; o[1] = (_Float16)f0.y;
    o[2] = (_Float16)f0.z; o[3] = (_Float16)f0.w;
    o[4] = (_Float16)f1.x; o[5] = (_Float16)f1.y;
    o[6] = (_Float16)f1.z; o[7] = (_Float16)f1.w;
    *(v8h*)(ef + i) = o;
  } else {                                    // ---- weight packs (9 blocks)
    int tid = (b - NLB - NEB) * 256 + threadIdx.x;
    if (tid < 1536){                          // w_hh: 24 frags (K=64: 2 frags)
      int f = tid >> 6, l = tid & 63;
      int jt = f >> 1, kf = f & 1;
      float sc = (jt < 8) ? SC_RZ : SC_N;     // exp2-arg scale folded in
      #pragma unroll
      for (int i = 0; i < 8; ++i){
        int row = jt * 16 + (l & 15);
        int col = kf * 32 + (l >> 4) * 8 + i;
        wpk[(size_t)tid * 8 + i] = (_Float16)(sc * whh[row * HS + col]);
      }
    } else if (tid < 1536 + 768){             // w_ih: 12 frags (K=32)
      int t2 = tid - 1536;
      int tile = t2 >> 6, l = t2 & 63;
      float sc = ((tile >> 2) < 2) ? SC_RZ : SC_N;
      #pragma unroll
      for (int i = 0; i < 8; ++i){
        int row = tile * 16 + (l & 15);
        int col = (l >> 4) * 8 + i;
        wpe[(size_t)t2 * 8 + i] = (_Float16)(sc * wih[row * ES + col]);
      }
    }
  }
}

// ---------------- K2: fused scan + scatter ----------------------------------
__global__ __launch_bounds__(1024) void k_scatter(const int* __restrict__ hist,
                                                  const int* __restrict__ len,
                                                  int* __restrict__ gcnt,
                                                  int* __restrict__ perm){
  __shared__ int buf[1024];
  __shared__ int offs[513];
  int i = threadIdx.x;
  buf[i] = (i < 513) ? hist[i] : 0;
  __syncthreads();
  for (int d = 1; d < 1024; d <<= 1){
    int v = (i >= d) ? buf[i - d] : 0;
    __syncthreads();
    buf[i] += v;
    __syncthreads();
  }
  if (i < 513) offs[i] = (i == 0) ? 0 : buf[i - 1];
  __syncthreads();
  int s = blockIdx.x * 1024 + i;
  int l = len[s];
  int pos = offs[l] + atomicAdd(&gcnt[l], 1);
  perm[pos] = s;
}

// ---------------- K3: recurrence (R1 structure + serial-chain cuts) ---------
// R3/R4/R5 established: sustained-residency schemes keep issue contention on
// the critical-path (longest) block and LOSE vs R1's decaying-residency
// schedule (R1 eff. L~1150 < R4's sustained L=1410). So: R1 structure kept
// verbatim; this round only shortens the per-step serial chain:
// (1) h ds_write moved BEFORE the gx MFMAs + emb prefetch (independent of h):
//     their issue (~80-100cyc) now covers the write latency, so the
//     lgkmcnt(0) before s_barrier is largely pre-drained.
// (2) gh MFMAs split-accumulated: Dr = mfma(a1,.,PRR) + mfma(a0,.,0) via
//     vector add instead of the 2-deep serial accumulate -> one MFMA latency
//     (~40cyc) off the ds_read -> gates critical path, for all three gates.
__global__ __launch_bounds__(256, 4) void k_gru(
    const int* __restrict__ x, const _Float16* __restrict__ ef,
    const _Float16* __restrict__ wpk, const _Float16* __restrict__ wpe,
    const float* __restrict__ bih, const float* __restrict__ bhh,
    const int* __restrict__ perm, const int* __restrict__ len,
    float* __restrict__ out)
{
  __shared__ __align__(16) _Float16 hb[2][16 * LDH];
  __shared__ unsigned short tok[(LSEQ + 2) * TS];   // transposed tokens
  int qt   = threadIdx.x >> 6;
  int w = blockIdx.x >> 8, cq = blockIdx.x & 255;
  int rank = w * 256 + ((w & 1) ? (255 - cq) : cq);   // 0 = longest
  int grp  = 1023 - rank;                             // ascending-sorted index
  int lane = threadIdx.x & 63;
  int q = lane >> 4, c = lane & 15;
  int uu = qt*16 + c;

  v8h bfh[3][2], bfe[3];
  #pragma unroll
  for (int g = 0; g < 3; ++g){
    int tile = g*4 + qt;
    #pragma unroll
    for (int kf = 0; kf < 2; ++kf)
      bfh[g][kf] = *(const v8h*)(wpk + ((size_t)(tile*2 + kf)*64 + lane)*8);
    bfe[g] = *(const v8h*)(wpe + ((size_t)tile*64 + lane)*8);
  }

  int sq[4], ln[4];
  #pragma unroll
  for (int r = 0; r < 4; ++r){
    int s = perm[grp * 16 + q*4 + r];
    sq[r] = s;
    ln[r] = len[s];
  }
  float br  = SC_RZ * (bih[uu]      + bhh[uu]);
  float bz  = SC_RZ * (bih[HS + uu] + bhh[HS + uu]);
  float ben = SC_N  *  bih[2*HS + uu];
  float bhn = SC_N  *  bhh[2*HS + uu];
  v4f brq  = {br, br, br, br};
  v4f bzq  = {bz, bz, bz, bz};
  v4f benq = {ben, ben, ben, ben};
  v4f bhnq = {bhn, bhn, bhn, bhn};
  const v4f zero4 = {0.f, 0.f, 0.f, 0.f};

  float h[4];
  #pragma unroll
  for (int r = 0; r < 4; ++r) h[r] = 0.f;

  for (int i = threadIdx.x; i < 16*LDH; i += 256) hb[0][i] = (_Float16)0.f;

  // stage tokens transposed: global reads coalesced; LDS writes 2-way (free).
  for (int j = threadIdx.x; j < 16*LSEQ; j += 256){
    int s = j >> 9, tt = j & (LSEQ-1);
    tok[tt*TS + s] = (unsigned short)x[(size_t)perm[grp*16 + s] * LSEQ + tt];
  }
  if (threadIdx.x < 32){                      // zero rows 512,513 (t+2 lookahead)
    tok[(LSEQ + (threadIdx.x >> 4))*TS + (threadIdx.x & 15)] = 0;
  }
  __syncthreads();

  int tmax = max(max(ln[0], ln[1]), max(ln[2], ln[3]));
  tmax = max(tmax, __shfl_xor(tmax, 16, 64));
  tmax = max(tmax, __shfl_xor(tmax, 32, 64));
  int tmin = min(min(ln[0], ln[1]), min(ln[2], ln[3]));
  tmin = min(tmin, __shfl_xor(tmin, 16, 64));
  tmin = min(tmin, __shfl_xor(tmin, 32, 64));

  v8h aec, aen;                       // emb frags: consume one, load the other
  v4f pra, prb, pza, pzb, dea, deb;   // e-partials: r, z, n (ping/pong)
  {
    int tk0 = tok[0*TS + c];
    aec = *(const v8h*)(ef + (size_t)tk0 * ES + q*8);
    pra = __builtin_amdgcn_mfma_f32_16x16x32_f16(aec, bfe[0], brq,  0,0,0);
    pza = __builtin_amdgcn_mfma_f32_16x16x32_f16(aec, bfe[1], bzq,  0,0,0);
    dea = __builtin_amdgcn_mfma_f32_16x16x32_f16(aec, bfe[2], benq, 0,0,0);
    int tk1 = tok[1*TS + c];
    aen = *(const v8h*)(ef + (size_t)tk1 * ES + q*8);   // emb for t=1
  }

  // ACONS = emb(t+1), loaded one full step ago; ALOAD <- emb(t+2) this step.
  // Order inside step: ds_reads -> split gh MFMAs -> gates -> h ds_write ->
  // gx MFMAs + emb load (cover write latency) -> lgkm-only barrier.
  #define GRU_STEP(FREEZE, ACONS, ALOAD, PRR, PRZ, DEN, PRRn, PRZn, DENn, RB, WB) \
  {                                                                            \
    int tkn = tok[(t + 2)*TS + c];                                             \
    v8h a0 = *(const v8h*)(&hb[RB][c*LDH + q*8]);                              \
    v8h a1 = *(const v8h*)(&hb[RB][c*LDH + 32 + q*8]);                         \
    v4f ur  = __builtin_amdgcn_mfma_f32_16x16x32_f16(a1, bfh[0][1], PRR, 0,0,0);\
    v4f vr  = __builtin_amdgcn_mfma_f32_16x16x32_f16(a0, bfh[0][0], zero4,0,0,0);\
    v4f uz  = __builtin_amdgcn_mfma_f32_16x16x32_f16(a1, bfh[1][1], PRZ, 0,0,0);\
    v4f vz  = __builtin_amdgcn_mfma_f32_16x16x32_f16(a0, bfh[1][0], zero4,0,0,0);\
    v4f uh  = __builtin_amdgcn_mfma_f32_16x16x32_f16(a1, bfh[2][1], bhnq,0,0,0);\
    v4f vh  = __builtin_amdgcn_mfma_f32_16x16x32_f16(a0, bfh[2][0], zero4,0,0,0);\
    v4f Dr  = ur + vr;                                                         \
    v4f Dz  = uz + vz;                                                         \
    v4f Dhn = uh + vh;                                                         \
    _Pragma("unroll")                                                          \
    for (int r = 0; r < 4; ++r){                                               \
      float rg   = __builtin_amdgcn_rcpf(1.f + __builtin_amdgcn_exp2f(Dr[r])); \
      float zg   = __builtin_amdgcn_rcpf(1.f + __builtin_amdgcn_exp2f(Dz[r])); \
      float te   = __builtin_amdgcn_exp2f(DEN[r] + rg * Dhn[r]);               \
      float ng   = fmaf(2.f, __builtin_amdgcn_rcpf(1.f + te), -1.f);           \
      float hnew = ng + zg * (h[r] - ng);                                      \
      h[r]       = (FREEZE && t >= ln[r]) ? h[r] : hnew;                       \
    }                                                                          \
    _Pragma("unroll")                                                          \
    for (int r = 0; r < 4; ++r)                                                \
      hb[WB][(q*4 + r)*LDH + uu] = (_Float16)h[r];                             \
    PRRn = __builtin_amdgcn_mfma_f32_16x16x32_f16(ACONS, bfe[0], brq,  0,0,0); \
    PRZn = __builtin_amdgcn_mfma_f32_16x16x32_f16(ACONS, bfe[1], bzq,  0,0,0); \
    DENn = __builtin_amdgcn_mfma_f32_16x16x32_f16(ACONS, bfe[2], benq, 0,0,0); \
    ALOAD = *(const v8h*)(ef + (size_t)tkn * ES + q*8);  /* emb t+2 */         \
    asm volatile("s_waitcnt lgkmcnt(0)" ::: "memory");                         \
    __builtin_amdgcn_s_barrier();                                              \
    asm volatile("" ::: "memory");                                             \
  }

  int t = 0;
  for (; t + 1 < tmin; ){   // no-freeze main loop (t and t+1 both < all ln)
    GRU_STEP(0, aen, aec, pra, pza, dea, prb, pzb, deb, 0, 1); ++t;
    GRU_STEP(0, aec, aen, prb, pzb, deb, pra, pza, dea, 1, 0); ++t;
  }
  for (; t + 1 < tmax; ){   // tail pairs with freeze (parity preserved)
    GRU_STEP(1, aen, aec, pra, pza, dea, prb, pzb, deb, 0, 1); ++t;
    GRU_STEP(1, aec, aen, prb, pzb, deb, pra, pza, dea, 1, 0); ++t;
  }
  if (t < tmax){
    GRU_STEP(1, aen, aec, pra, pza, dea, prb, pzb, deb, 0, 1); ++t;
  }
  #undef GRU_STEP

  #pragma unroll
  for (int r = 0; r < 4; ++r)
    out[(size_t)sq[r] * HS + uu] = h[r];
}

extern "C" void kernel_launch(void* const* d_in, const int* in_sizes, int n_in,
                              void* d_out, int out_size, void* d_ws, size_t ws_size,
                              hipStream_t stream){
  const int*   x   = (const int*)  d_in[0];
  const float* emb = (const float*)d_in[1];
  const float* wih = (const float*)d_in[2];
  const float* whh = (const float*)d_in[3];
  const float* bih = (const float*)d_in[4];
  const float* bhh = (const float*)d_in[5];
  float* out = (float*)d_out;

  char* ws = (char*)d_ws;
  size_t off = 0;
  _Float16* ef  = (_Float16*)(ws + off);  off += (size_t)VOCAB * ES * sizeof(_Float16);
  _Float16* wpk = (_Float16*)(ws + off);  off += (size_t)24 * 64 * 8 * sizeof(_Float16);
  _Float16* wpe = (_Float16*)(ws + off);  off += (size_t)12 * 64 * 8 * sizeof(_Float16);
  off = (off + 255) & ~(size_t)255;
  int* len  = (int*)(ws + off);           off += (size_t)N_SEQ * sizeof(int);
  int* perm = (int*)(ws + off);           off += (size_t)N_SEQ * sizeof(int);
  int* hist = (int*)(ws + off);           off += 513 * sizeof(int);
  int* gcnt = (int*)(ws + off);           off += 513 * sizeof(int);

  hipMemsetAsync(hist, 0, 2 * 513 * sizeof(int), stream);   // hist + gcnt
  k_prep   <<<NLB + NEB + 9, 256, 0, stream>>>(x, emb, whh, wih, len, hist, ef, wpk, wpe);
  k_scatter<<<N_SEQ / 1024, 1024, 0, stream>>>(hist, len, gcnt, perm);
  k_gru    <<<N_SEQ / 16,    256, 0, stream>>>(x, ef, wpk, wpe, bih, bhh, perm, len, out);
}